// Round 1
// baseline (57.204 us; speedup 1.0000x reference)
//
#include <hip/hip_runtime.h>
#include <math.h>

#define B 8
#define S 4096
#define H 1024
#define NSEG 64
#define NPARA 32
#define NA 8

// ---------------------------------------------------------------------------
// Kernel 1: per-row 4-way dot products.
// For each row r (= b*S+s) of sequence_output compute:
//   d0 = row . Wqa[:,0], d1 = row . Wqa[:,1], d2 = row . Wsp, d3 = row . Wrank
// One wave (64 lanes) per row, float4 loads, weights preloaded in registers.
// ---------------------------------------------------------------------------
__global__ __launch_bounds__(256) void dots_kernel(
    const float* __restrict__ seq,
    const float* __restrict__ Wqa,
    const float* __restrict__ Wsp,
    const float* __restrict__ Wrank,
    float* __restrict__ out, int nrows)
{
    const int lane = threadIdx.x & 63;
    const int wid  = (blockIdx.x * blockDim.x + threadIdx.x) >> 6;
    const int nw   = (gridDim.x * blockDim.x) >> 6;

    // Preload weights: lane handles float4 chunks at index lane + 64*c, c=0..3
    float wq0[4][4], wq1[4][4];
    float4 wspv[4], wrkv[4];
#pragma unroll
    for (int c = 0; c < 4; ++c) {
        int h0 = (lane + 64 * c) * 4;
#pragma unroll
        for (int j = 0; j < 4; ++j) {
            wq0[c][j] = Wqa[(h0 + j) * 2 + 0];
            wq1[c][j] = Wqa[(h0 + j) * 2 + 1];
        }
        wspv[c] = *(const float4*)(Wsp + h0);
        wrkv[c] = *(const float4*)(Wrank + h0);
    }

    for (int r = wid; r < nrows; r += nw) {
        const float4* row = (const float4*)(seq + (size_t)r * H);
        float a0 = 0.f, a1 = 0.f, a2 = 0.f, a3 = 0.f;
#pragma unroll
        for (int c = 0; c < 4; ++c) {
            float4 v = row[lane + 64 * c];
            a0 += v.x * wq0[c][0] + v.y * wq0[c][1] + v.z * wq0[c][2] + v.w * wq0[c][3];
            a1 += v.x * wq1[c][0] + v.y * wq1[c][1] + v.z * wq1[c][2] + v.w * wq1[c][3];
            a2 += v.x * wspv[c].x + v.y * wspv[c].y + v.z * wspv[c].z + v.w * wspv[c].w;
            a3 += v.x * wrkv[c].x + v.y * wrkv[c].y + v.z * wrkv[c].z + v.w * wrkv[c].w;
        }
#pragma unroll
        for (int off = 32; off > 0; off >>= 1) {
            a0 += __shfl_xor(a0, off);
            a1 += __shfl_xor(a1, off);
            a2 += __shfl_xor(a2, off);
            a3 += __shfl_xor(a3, off);
        }
        if (lane == 0) {
            *(float4*)(out + (size_t)r * 4) = make_float4(a0, a1, a2, a3);
        }
    }
}

// ---------------------------------------------------------------------------
// Block-wide reduction helper (256 threads).
// ---------------------------------------------------------------------------
__device__ __forceinline__ float blk_reduce(float v, float* red, int t, bool ismax)
{
    red[t] = v;
    __syncthreads();
#pragma unroll
    for (int s = 128; s > 0; s >>= 1) {
        if (t < s) red[t] = ismax ? fmaxf(red[t], red[t + s]) : (red[t] + red[t + s]);
        __syncthreads();
    }
    float r = red[0];
    __syncthreads();
    return r;
}

// ListMLE over shared arrays fs/fl of length n (n <= 65); all 256 threads call.
__device__ float listmle_block(const float* fs, const float* fl, float* se,
                               int n, float* red, int t)
{
    if (t < n) se[t] = (fl[t] != -1.0f) ? expf(fs[t]) : 0.0f;
    __syncthreads();
    float lp = 0.0f;
    if (t < n && fl[t] >= 0.5f) {
        float fj = fl[t];
        float rest = 0.0f;
        for (int k = 0; k < n; ++k)
            if (fl[k] < fj) rest += se[k];
        lp = fs[t] - logf(se[t] + rest);
    }
    float tot = blk_reduce(lp, red, t, false);
    return -tot;
}

// ---------------------------------------------------------------------------
// Kernel 2: one block per batch. Computes logsumexp of start/end logits,
// segment means via LDS prefix scan, both ListMLE losses, and the span loss
// log-term. Writes partials[b*3 + {0:rank,1:sp,2:span_logm}].
// ---------------------------------------------------------------------------
__global__ __launch_bounds__(256) void batch_kernel(
    const float* __restrict__ scores,      // (B,S,4)
    const int*   __restrict__ tt,          // (B,S)
    const int*   __restrict__ sent_starts, // (B,NSEG+1)
    const int*   __restrict__ para_starts, // (B,NPARA)
    const float* __restrict__ para_labels, // (B,NPARA)
    const float* __restrict__ sp_labels,   // (B,NSEG)
    const int*   __restrict__ starts,      // (B,NA)
    const int*   __restrict__ ends,        // (B,NA)
    const float* __restrict__ bqa,
    const float* __restrict__ brank,
    const float* __restrict__ bsp,
    float* __restrict__ partials)
{
    const int b = blockIdx.x;
    const int t = threadIdx.x;

    __shared__ float sm[S + 1];          // exclusive prefix sums of d_sp
    __shared__ float red[256];
    __shared__ float fsb[1 + NSEG], flb[1 + NSEG], seb[1 + NSEG];

    const float* sb  = scores + (size_t)b * S * 4;
    const int*   ttb = tt + b * S;
    const float  bq0 = bqa[0], bq1 = bqa[1], brk = brank[0], bs = bsp[0];

    // ---- logsumexp of masked start/end logits --------------------------------
    float m0 = -INFINITY, m1 = -INFINITY;
    for (int s = t; s < S; s += 256) {
        if (ttb[s] == 1) {
            m0 = fmaxf(m0, sb[s * 4 + 0] + bq0);
            m1 = fmaxf(m1, sb[s * 4 + 1] + bq1);
        }
    }
    m0 = blk_reduce(m0, red, t, true);
    m1 = blk_reduce(m1, red, t, true);
    float e0 = 0.f, e1 = 0.f;
    for (int s = t; s < S; s += 256) {
        if (ttb[s] == 1) {
            e0 += expf(sb[s * 4 + 0] + bq0 - m0);
            e1 += expf(sb[s * 4 + 1] + bq1 - m1);
        }
    }
    e0 = blk_reduce(e0, red, t, false);
    e1 = blk_reduce(e1, red, t, false);
    const float lse0 = m0 + logf(e0);
    const float lse1 = m1 + logf(e1);

    // ---- exclusive prefix scan of d_sp over S --------------------------------
    {
        float vals[16];
        float run = 0.f;
        const int base = t * 16;
#pragma unroll
        for (int i = 0; i < 16; ++i) {
            run += sb[(base + i) * 4 + 2];
            vals[i] = run;
        }
        red[t] = run;
        __syncthreads();
        if (t == 0) {
            float acc = 0.f;
            for (int i = 0; i < 256; ++i) { float x = red[i]; red[i] = acc; acc += x; }
        }
        __syncthreads();
        float off = red[t];
#pragma unroll
        for (int i = 0; i < 16; ++i) sm[base + i + 1] = off + vals[i];
        if (t == 0) sm[0] = 0.f;
        __syncthreads();
    }

    // ---- sp ListMLE ----------------------------------------------------------
    if (t == 0) { fsb[0] = sb[2] + bs; flb[0] = 0.5f; }   // sent_thres (row 0)
    if (t < NSEG) {
        int st = sent_starts[b * (NSEG + 1) + t];
        int en = sent_starts[b * (NSEG + 1) + t + 1];
        int stc = min(max(st, 0), S);
        int enc = max(min(max(en, 0), S), stc + 1);
        float score;
        if (en != -1) {
            int encc = min(enc, S);
            score = (sm[encc] - sm[stc]) / (float)(enc - stc) + bs;
        } else {
            score = (sm[S] - sm[S - 1]) + bs;               // d_sp at last row
        }
        fsb[1 + t] = score;
        flb[1 + t] = sp_labels[b * NSEG + t];
    }
    __syncthreads();
    float sp_loss_b = listmle_block(fsb, flb, seb, 1 + NSEG, red, t);

    // ---- rank ListMLE --------------------------------------------------------
    if (t == 0) { fsb[0] = sb[3] + brk; flb[0] = 0.5f; }  // rank_thres (row 0)
    if (t < NPARA) {
        int ps = para_starts[b * NPARA + t];
        fsb[1 + t] = sb[(size_t)ps * 4 + 3] + brk;
        flb[1 + t] = para_labels[b * NPARA + t];
    }
    __syncthreads();
    float rank_loss_b = listmle_block(fsb, flb, seb, 1 + NPARA, red, t);

    // ---- span loss -----------------------------------------------------------
    if (t == 0) {
        float msum = 0.f;
        for (int a = 0; a < NA; ++a) {
            int tsv = starts[b * NA + a];
            int tev = ends[b * NA + a];
            float lt = 0.f;
            if (tsv != -1) {
                int sf = min(max(tsv, 0), S - 1);
                float sl = (ttb[sf] == 1) ? (sb[sf * 4 + 0] + bq0) : -INFINITY;
                lt += -(sl - lse0);
            }
            if (tev != -1) {
                int sf = min(max(tev, 0), S - 1);
                float el = (ttb[sf] == 1) ? (sb[sf * 4 + 1] + bq1) : -INFINITY;
                lt += -(el - lse1);
            }
            float lp = -lt;
            if (lp == 0.0f) lp = -INFINITY;
            msum += expf(lp);
        }
        partials[b * 3 + 0] = rank_loss_b;
        partials[b * 3 + 1] = sp_loss_b;
        partials[b * 3 + 2] = (msum > 0.f) ? logf(msum) : 0.f;
    }
}

// ---------------------------------------------------------------------------
// Kernel 3: final sum over batches -> (loss, rank_loss, sp_loss)
// ---------------------------------------------------------------------------
__global__ void finalize_kernel(const float* __restrict__ partials,
                                float* __restrict__ out)
{
    if (blockIdx.x == 0 && threadIdx.x == 0) {
        float rank = 0.f, sp = 0.f, spanlog = 0.f;
        for (int b = 0; b < B; ++b) {
            rank    += partials[b * 3 + 0];
            sp      += partials[b * 3 + 1];
            spanlog += partials[b * 3 + 2];
        }
        float span = -spanlog;
        out[0] = rank + span + sp;
        out[1] = rank;
        out[2] = sp;
    }
}

extern "C" void kernel_launch(void* const* d_in, const int* in_sizes, int n_in,
                              void* d_out, int out_size, void* d_ws, size_t ws_size,
                              hipStream_t stream)
{
    const float* seq         = (const float*)d_in[0];
    const int*   tt          = (const int*)  d_in[1];
    const int*   sent_starts = (const int*)  d_in[2];
    const int*   para_starts = (const int*)  d_in[3];
    const float* para_labels = (const float*)d_in[4];
    const float* sp_labels   = (const float*)d_in[5];
    const int*   starts      = (const int*)  d_in[6];
    const int*   ends        = (const int*)  d_in[7];
    const float* Wqa         = (const float*)d_in[8];
    const float* bqa         = (const float*)d_in[9];
    const float* Wrank       = (const float*)d_in[10];
    const float* brank       = (const float*)d_in[11];
    const float* Wsp         = (const float*)d_in[12];
    const float* bsp         = (const float*)d_in[13];

    float* out      = (float*)d_out;
    float* scores   = (float*)d_ws;                 // B*S*4 floats (512 KB)
    float* partials = scores + (size_t)B * S * 4;   // B*3 floats

    const int nrows = B * S;
    dots_kernel<<<2048, 256, 0, stream>>>(seq, Wqa, Wsp, Wrank, scores, nrows);
    batch_kernel<<<B, 256, 0, stream>>>(scores, tt, sent_starts, para_starts,
                                        para_labels, sp_labels, starts, ends,
                                        bqa, brank, bsp, partials);
    finalize_kernel<<<1, 64, 0, stream>>>(partials, out);
}

// Round 2
// 52.285 us; speedup vs baseline: 1.0941x; 1.0941x over previous
//
#include <hip/hip_runtime.h>
#include <math.h>

#define B 8
#define S 4096
#define H 1024
#define NSEG 64
#define NPARA 32
#define NA 8
#define BS (B * S)
#define PAD(i) ((i) + ((i) >> 4))

// ---------------------------------------------------------------------------
// Kernel 1: per-row 4-way dot products, planar output.
// plane0 = row.Wqa[:,0], plane1 = row.Wqa[:,1], plane2 = row.Wsp,
// plane3 = row.Wrank.  One wave per row, float4 loads, weights in registers.
// Block 0 thread 0 also zeroes the 3 output scalars (batch_kernel atomicAdds).
// ---------------------------------------------------------------------------
__global__ __launch_bounds__(256) void dots_kernel(
    const float* __restrict__ seq,
    const float* __restrict__ Wqa,
    const float* __restrict__ Wsp,
    const float* __restrict__ Wrank,
    float* __restrict__ scores, float* __restrict__ out, int nrows)
{
    if (blockIdx.x == 0 && threadIdx.x == 0) {
        out[0] = 0.f; out[1] = 0.f; out[2] = 0.f;
    }
    const int lane = threadIdx.x & 63;
    const int wid  = (blockIdx.x * blockDim.x + threadIdx.x) >> 6;
    const int nw   = (gridDim.x * blockDim.x) >> 6;

    float wq0[4][4], wq1[4][4];
    float4 wspv[4], wrkv[4];
#pragma unroll
    for (int c = 0; c < 4; ++c) {
        int h0 = (lane + 64 * c) * 4;
#pragma unroll
        for (int j = 0; j < 4; ++j) {
            wq0[c][j] = Wqa[(h0 + j) * 2 + 0];
            wq1[c][j] = Wqa[(h0 + j) * 2 + 1];
        }
        wspv[c] = *(const float4*)(Wsp + h0);
        wrkv[c] = *(const float4*)(Wrank + h0);
    }

    for (int r = wid; r < nrows; r += nw) {
        const float4* row = (const float4*)(seq + (size_t)r * H);
        float a0 = 0.f, a1 = 0.f, a2 = 0.f, a3 = 0.f;
#pragma unroll
        for (int c = 0; c < 4; ++c) {
            float4 v = row[lane + 64 * c];
            a0 += v.x * wq0[c][0] + v.y * wq0[c][1] + v.z * wq0[c][2] + v.w * wq0[c][3];
            a1 += v.x * wq1[c][0] + v.y * wq1[c][1] + v.z * wq1[c][2] + v.w * wq1[c][3];
            a2 += v.x * wspv[c].x + v.y * wspv[c].y + v.z * wspv[c].z + v.w * wspv[c].w;
            a3 += v.x * wrkv[c].x + v.y * wrkv[c].y + v.z * wrkv[c].z + v.w * wrkv[c].w;
        }
#pragma unroll
        for (int off = 32; off > 0; off >>= 1) {
            a0 += __shfl_xor(a0, off);
            a1 += __shfl_xor(a1, off);
            a2 += __shfl_xor(a2, off);
            a3 += __shfl_xor(a3, off);
        }
        if (lane == 0) {
            scores[0 * BS + r] = a0;
            scores[1 * BS + r] = a1;
            scores[2 * BS + r] = a2;
            scores[3 * BS + r] = a3;
        }
    }
}

// ---------------------------------------------------------------------------
// Reductions: wave shuffle + 4-entry LDS combine (2 barriers total).
// ---------------------------------------------------------------------------
__device__ __forceinline__ float2 blk_reduce2(float2 v, bool ismax,
                                              float2* wred, int t)
{
    const int lane = t & 63, w = t >> 6;
#pragma unroll
    for (int off = 32; off > 0; off >>= 1) {
        float x = __shfl_xor(v.x, off);
        float y = __shfl_xor(v.y, off);
        if (ismax) { v.x = fmaxf(v.x, x); v.y = fmaxf(v.y, y); }
        else       { v.x += x;            v.y += y; }
    }
    if (lane == 0) wred[w] = v;
    __syncthreads();
    float2 r = wred[0];
#pragma unroll
    for (int i = 1; i < 4; ++i) {
        float2 u = wred[i];
        if (ismax) { r.x = fmaxf(r.x, u.x); r.y = fmaxf(r.y, u.y); }
        else       { r.x += u.x;            r.y += u.y; }
    }
    __syncthreads();
    return r;
}

__device__ __forceinline__ float blk_reduce1(float v, float* wred1, int t)
{
    const int lane = t & 63, w = t >> 6;
#pragma unroll
    for (int off = 32; off > 0; off >>= 1) v += __shfl_xor(v, off);
    if (lane == 0) wred1[w] = v;
    __syncthreads();
    float r = wred1[0] + wred1[1] + wred1[2] + wred1[3];
    __syncthreads();
    return r;
}

// ListMLE over shared arrays fs/fl of length n (n <= 65); all 256 threads call.
__device__ float listmle_block(const float* fs, const float* fl, float* se,
                               int n, float* wred1, int t)
{
    if (t < n) se[t] = (fl[t] != -1.0f) ? expf(fs[t]) : 0.0f;
    __syncthreads();
    float lp = 0.0f;
    if (t < n && fl[t] >= 0.5f) {
        float fj = fl[t];
        float rest = 0.0f;
        for (int k = 0; k < n; ++k)
            if (fl[k] < fj) rest += se[k];
        lp = fs[t] - logf(se[t] + rest);
    }
    float tot = blk_reduce1(lp, wred1, t);
    return -tot;
}

// ---------------------------------------------------------------------------
// Kernel 2: one block per batch; fused LSE + scan + 2x ListMLE + span loss;
// atomicAdds (rank, sp, rank+sp-logm) into out.
// ---------------------------------------------------------------------------
__global__ __launch_bounds__(256) void batch_kernel(
    const float* __restrict__ scores,      // planar (4, B*S)
    const int*   __restrict__ tt,
    const int*   __restrict__ sent_starts,
    const int*   __restrict__ para_starts,
    const float* __restrict__ para_labels,
    const float* __restrict__ sp_labels,
    const int*   __restrict__ starts,
    const int*   __restrict__ ends,
    const float* __restrict__ bqa,
    const float* __restrict__ brank,
    const float* __restrict__ bsp,
    float* __restrict__ out)
{
    const int b = blockIdx.x;
    const int t = threadIdx.x;

    __shared__ float  a[PAD(S) + 1];       // padded prefix-sum array
    __shared__ float2 wred[4];
    __shared__ float  wred1[4];
    __shared__ float  fsb[1 + NSEG], flb[1 + NSEG], seb[1 + NSEG];

    const float* p0 = scores + 0 * BS + b * S;
    const float* p1 = scores + 1 * BS + b * S;
    const float* p2 = scores + 2 * BS + b * S;
    const float* p3 = scores + 3 * BS + b * S;
    const int*   ttb = tt + b * S;
    const float  bq0 = bqa[0], bq1 = bqa[1], brk = brank[0], bs = bsp[0];

    // ---- masked logsumexp of start/end logits (coalesced planar reads) ------
    float2 m = make_float2(-INFINITY, -INFINITY);
    for (int s = t; s < S; s += 256) {
        if (ttb[s] == 1) {
            m.x = fmaxf(m.x, p0[s] + bq0);
            m.y = fmaxf(m.y, p1[s] + bq1);
        }
    }
    m = blk_reduce2(m, true, wred, t);
    float2 e = make_float2(0.f, 0.f);
    for (int s = t; s < S; s += 256) {
        if (ttb[s] == 1) {
            e.x += expf(p0[s] + bq0 - m.x);
            e.y += expf(p1[s] + bq1 - m.y);
        }
    }
    e = blk_reduce2(e, false, wred, t);
    const float lse0 = m.x + logf(e.x);
    const float lse1 = m.y + logf(e.y);

    // ---- exclusive prefix scan of p2 over S ---------------------------------
    {
        // stage into padded LDS (coalesced global read)
        for (int s = t; s < S; s += 256) a[PAD(s)] = p2[s];
        __syncthreads();
        // per-thread local scan of 16-chunk (bank-conflict-free via padding)
        float vals[16];
        float run = 0.f;
        const int base = t * 16;
#pragma unroll
        for (int i = 0; i < 16; ++i) {
            run += a[PAD(base + i)];
            vals[i] = run;
        }
        // wave-level inclusive scan of per-thread sums
        const int lane = t & 63, w = t >> 6;
        float v = run;
#pragma unroll
        for (int off = 1; off < 64; off <<= 1) {
            float u = __shfl_up(v, off, 64);
            if (lane >= off) v += u;
        }
        if (lane == 63) wred1[w] = v;
        __syncthreads();
        float woff = 0.f;
        for (int i = 0; i < w; ++i) woff += wred1[i];
        const float excl = woff + v - run;   // exclusive offset for this thread
        __syncthreads();                      // all reads of a[] done
#pragma unroll
        for (int i = 0; i < 16; ++i) a[PAD(base + i + 1)] = excl + vals[i];
        if (t == 0) a[PAD(0)] = 0.f;
        __syncthreads();
    }

    // ---- sp ListMLE ---------------------------------------------------------
    if (t == 0) { fsb[0] = p2[0] + bs; flb[0] = 0.5f; }
    if (t < NSEG) {
        int st = sent_starts[b * (NSEG + 1) + t];
        int en = sent_starts[b * (NSEG + 1) + t + 1];
        int stc = min(max(st, 0), S);
        int enc = max(min(max(en, 0), S), stc + 1);
        float score;
        if (en != -1) {
            int encc = min(enc, S);
            score = (a[PAD(encc)] - a[PAD(stc)]) / (float)(enc - stc) + bs;
        } else {
            score = (a[PAD(S)] - a[PAD(S - 1)]) + bs;   // d_sp at last row
        }
        fsb[1 + t] = score;
        flb[1 + t] = sp_labels[b * NSEG + t];
    }
    __syncthreads();
    float sp_loss_b = listmle_block(fsb, flb, seb, 1 + NSEG, wred1, t);

    // ---- rank ListMLE -------------------------------------------------------
    if (t == 0) { fsb[0] = p3[0] + brk; flb[0] = 0.5f; }
    if (t < NPARA) {
        int ps = para_starts[b * NPARA + t];
        fsb[1 + t] = p3[ps] + brk;
        flb[1 + t] = para_labels[b * NPARA + t];
    }
    __syncthreads();
    float rank_loss_b = listmle_block(fsb, flb, seb, 1 + NPARA, wred1, t);

    // ---- span loss + output accumulation ------------------------------------
    if (t == 0) {
        float msum = 0.f;
        for (int aidx = 0; aidx < NA; ++aidx) {
            int tsv = starts[b * NA + aidx];
            int tev = ends[b * NA + aidx];
            float lt = 0.f;
            if (tsv != -1) {
                int sf = min(max(tsv, 0), S - 1);
                float sl = (ttb[sf] == 1) ? (p0[sf] + bq0) : -INFINITY;
                lt += -(sl - lse0);
            }
            if (tev != -1) {
                int sf = min(max(tev, 0), S - 1);
                float el = (ttb[sf] == 1) ? (p1[sf] + bq1) : -INFINITY;
                lt += -(el - lse1);
            }
            float lp = -lt;
            if (lp == 0.0f) lp = -INFINITY;
            msum += expf(lp);
        }
        float logm = (msum > 0.f) ? logf(msum) : 0.f;
        atomicAdd(out + 0, rank_loss_b + sp_loss_b - logm);
        atomicAdd(out + 1, rank_loss_b);
        atomicAdd(out + 2, sp_loss_b);
    }
}

extern "C" void kernel_launch(void* const* d_in, const int* in_sizes, int n_in,
                              void* d_out, int out_size, void* d_ws, size_t ws_size,
                              hipStream_t stream)
{
    const float* seq         = (const float*)d_in[0];
    const int*   tt          = (const int*)  d_in[1];
    const int*   sent_starts = (const int*)  d_in[2];
    const int*   para_starts = (const int*)  d_in[3];
    const float* para_labels = (const float*)d_in[4];
    const float* sp_labels   = (const float*)d_in[5];
    const int*   starts      = (const int*)  d_in[6];
    const int*   ends        = (const int*)  d_in[7];
    const float* Wqa         = (const float*)d_in[8];
    const float* bqa         = (const float*)d_in[9];
    const float* Wrank       = (const float*)d_in[10];
    const float* brank       = (const float*)d_in[11];
    const float* Wsp         = (const float*)d_in[12];
    const float* bsp         = (const float*)d_in[13];

    float* out    = (float*)d_out;
    float* scores = (float*)d_ws;   // planar (4, B*S) floats = 512 KB

    dots_kernel<<<2048, 256, 0, stream>>>(seq, Wqa, Wsp, Wrank, scores, out, BS);
    batch_kernel<<<B, 256, 0, stream>>>(scores, tt, sent_starts, para_starts,
                                        para_labels, sp_labels, starts, ends,
                                        bqa, brank, bsp, out);
}

// Round 3
// 39.883 us; speedup vs baseline: 1.4343x; 1.3110x over previous
//
#include <hip/hip_runtime.h>
#include <math.h>

#define B 8
#define S 4096
#define H 1024
#define NSEG 64
#define NPARA 32
#define NA 8
#define BS (B * S)
#define PAD(i) ((i) + ((i) >> 4))
#define ROWS_PER_BLK 16
#define BLKS_PER_B (S / ROWS_PER_BLK)      // 256
#define NBLK (B * BLKS_PER_B)              // 2048

// online-LSE merge: x = running max (m), y = running scaled sum (s)
__device__ __forceinline__ float2 lse_merge(float2 A, float2 Bv)
{
    float m = fmaxf(A.x, Bv.x);
    float s = 0.f;
    if (A.y > 0.f)  s += A.y * expf(A.x - m);
    if (Bv.y > 0.f) s += Bv.y * expf(Bv.x - m);
    return make_float2(m, s);
}

// ---------------------------------------------------------------------------
// Kernel 1: per-row 4-way dots + fused online masked logsumexp partials.
// Block k handles 16 contiguous rows of batch k/256. One wave per 4 rows.
// Outputs: planar scores (4, B*S) and per-block LSE partial float4
// (m0,s0,m1,s1) for the start/end logits.
// ---------------------------------------------------------------------------
__global__ __launch_bounds__(256) void dots_kernel(
    const float* __restrict__ seq,
    const float* __restrict__ Wqa,
    const float* __restrict__ Wsp,
    const float* __restrict__ Wrank,
    const int*   __restrict__ tt,
    float* __restrict__ scores,
    float4* __restrict__ lse_part,
    float* __restrict__ out)
{
    if (blockIdx.x == 0 && threadIdx.x == 0) {
        out[0] = 0.f; out[1] = 0.f; out[2] = 0.f;
    }
    const int blk   = blockIdx.x;
    const int b     = blk >> 8;                 // batch
    const int rbase = (blk & 255) * ROWS_PER_BLK;
    const int w     = threadIdx.x >> 6;
    const int lane  = threadIdx.x & 63;

    __shared__ float  blkres[4][ROWS_PER_BLK];
    __shared__ float4 lsep[4];

    // preload weights (lane handles float4 chunks lane + 64*c)
    float wq0[4][4], wq1[4][4];
    float4 wspv[4], wrkv[4];
#pragma unroll
    for (int c = 0; c < 4; ++c) {
        int h0 = (lane + 64 * c) * 4;
#pragma unroll
        for (int j = 0; j < 4; ++j) {
            wq0[c][j] = Wqa[(h0 + j) * 2 + 0];
            wq1[c][j] = Wqa[(h0 + j) * 2 + 1];
        }
        wspv[c] = *(const float4*)(Wsp + h0);
        wrkv[c] = *(const float4*)(Wrank + h0);
    }

    const int* ttb = tt + b * S;
    float m0 = -INFINITY, s0 = 0.f, m1 = -INFINITY, s1 = 0.f;

    for (int i = 0; i < 4; ++i) {
        const int srow = rbase + w * 4 + i;
        const float4* row = (const float4*)(seq + ((size_t)b * S + srow) * H);
        float a0 = 0.f, a1 = 0.f, a2 = 0.f, a3 = 0.f;
#pragma unroll
        for (int c = 0; c < 4; ++c) {
            float4 v = row[lane + 64 * c];
            a0 += v.x * wq0[c][0] + v.y * wq0[c][1] + v.z * wq0[c][2] + v.w * wq0[c][3];
            a1 += v.x * wq1[c][0] + v.y * wq1[c][1] + v.z * wq1[c][2] + v.w * wq1[c][3];
            a2 += v.x * wspv[c].x + v.y * wspv[c].y + v.z * wspv[c].z + v.w * wspv[c].w;
            a3 += v.x * wrkv[c].x + v.y * wrkv[c].y + v.z * wrkv[c].z + v.w * wrkv[c].w;
        }
#pragma unroll
        for (int off = 32; off > 0; off >>= 1) {
            a0 += __shfl_xor(a0, off);
            a1 += __shfl_xor(a1, off);
            a2 += __shfl_xor(a2, off);
            a3 += __shfl_xor(a3, off);
        }
        // fused online masked LSE (lane-uniform, bias dropped: shift-invariant)
        if (ttb[srow] == 1) {
            float mn = fmaxf(m0, a0);
            s0 = s0 * expf(m0 - mn) + expf(a0 - mn); m0 = mn;
            mn = fmaxf(m1, a1);
            s1 = s1 * expf(m1 - mn) + expf(a1 - mn); m1 = mn;
        }
        if (lane == 0) {
            const int idx = w * 4 + i;
            blkres[0][idx] = a0; blkres[1][idx] = a1;
            blkres[2][idx] = a2; blkres[3][idx] = a3;
        }
    }
    if (lane == 0) lsep[w] = make_float4(m0, s0, m1, s1);
    __syncthreads();

    const int t = threadIdx.x;
    if (t < 64) {   // coalesced score writes: 4 planes x 16 floats
        const int p = t >> 4, idx = t & 15;
        scores[p * BS + b * S + rbase + idx] = blkres[p][idx];
    }
    if (t == 0) {   // merge the 4 wave partials
        float2 L0 = make_float2(lsep[0].x, lsep[0].y);
        float2 L1 = make_float2(lsep[0].z, lsep[0].w);
#pragma unroll
        for (int i = 1; i < 4; ++i) {
            L0 = lse_merge(L0, make_float2(lsep[i].x, lsep[i].y));
            L1 = lse_merge(L1, make_float2(lsep[i].z, lsep[i].w));
        }
        lse_part[blk] = make_float4(L0.x, L0.y, L1.x, L1.y);
    }
}

// ---------------------------------------------------------------------------
// block reduce (sum) for ListMLE
// ---------------------------------------------------------------------------
__device__ __forceinline__ float blk_reduce1(float v, float* wred1, int t)
{
    const int lane = t & 63, w = t >> 6;
#pragma unroll
    for (int off = 32; off > 0; off >>= 1) v += __shfl_xor(v, off);
    if (lane == 0) wred1[w] = v;
    __syncthreads();
    float r = wred1[0] + wred1[1] + wred1[2] + wred1[3];
    __syncthreads();
    return r;
}

__device__ float listmle_block(const float* fs, const float* fl, float* se,
                               int n, float* wred1, int t)
{
    if (t < n) se[t] = (fl[t] != -1.0f) ? expf(fs[t]) : 0.0f;
    __syncthreads();
    float lp = 0.0f;
    if (t < n && fl[t] >= 0.5f) {
        float fj = fl[t];
        float rest = 0.0f;
        for (int k = 0; k < n; ++k)
            if (fl[k] < fj) rest += se[k];
        lp = fs[t] - logf(se[t] + rest);
    }
    float tot = blk_reduce1(lp, wred1, t);
    return -tot;
}

// ---------------------------------------------------------------------------
// Kernel 2: one block per batch. Merge LSE partials (4KB), prefix-scan p2,
// 2x ListMLE, parallel span loss; atomicAdd into out.
// ---------------------------------------------------------------------------
__global__ __launch_bounds__(256) void batch_kernel(
    const float*  __restrict__ scores,
    const float4* __restrict__ lse_part,
    const int*    __restrict__ tt,
    const int*    __restrict__ sent_starts,
    const int*    __restrict__ para_starts,
    const float*  __restrict__ para_labels,
    const float*  __restrict__ sp_labels,
    const int*    __restrict__ starts,
    const int*    __restrict__ ends,
    float* __restrict__ out)
{
    const int b = blockIdx.x;
    const int t = threadIdx.x;
    const int lane = t & 63, w = t >> 6;

    __shared__ float  a[PAD(S) + 1];
    __shared__ float4 lsew[4];
    __shared__ float  wred1[4];
    __shared__ float  fsb[1 + NSEG], flb[1 + NSEG], seb[1 + NSEG];
    __shared__ float  lse_sh[2];

    const float* p0 = scores + 0 * BS + b * S;
    const float* p1 = scores + 1 * BS + b * S;
    const float* p2 = scores + 2 * BS + b * S;
    const float* p3 = scores + 3 * BS + b * S;
    const int*   ttb = tt + b * S;

    // ---- merge 256 LSE partials ---------------------------------------------
    {
        float4 P = lse_part[b * BLKS_PER_B + t];
        float2 L0 = make_float2(P.x, P.y);
        float2 L1 = make_float2(P.z, P.w);
#pragma unroll
        for (int off = 32; off > 0; off >>= 1) {
            float2 O0 = make_float2(__shfl_xor(L0.x, off), __shfl_xor(L0.y, off));
            float2 O1 = make_float2(__shfl_xor(L1.x, off), __shfl_xor(L1.y, off));
            L0 = lse_merge(L0, O0);
            L1 = lse_merge(L1, O1);
        }
        if (lane == 0) lsew[w] = make_float4(L0.x, L0.y, L1.x, L1.y);
        __syncthreads();
        if (t == 0) {
            float2 M0 = make_float2(lsew[0].x, lsew[0].y);
            float2 M1 = make_float2(lsew[0].z, lsew[0].w);
#pragma unroll
            for (int i = 1; i < 4; ++i) {
                M0 = lse_merge(M0, make_float2(lsew[i].x, lsew[i].y));
                M1 = lse_merge(M1, make_float2(lsew[i].z, lsew[i].w));
            }
            lse_sh[0] = M0.x + logf(M0.y);
            lse_sh[1] = M1.x + logf(M1.y);
        }
    }

    // ---- exclusive prefix scan of p2 over S ---------------------------------
    {
        for (int s = t; s < S; s += 256) a[PAD(s)] = p2[s];
        __syncthreads();
        float vals[16];
        float run = 0.f;
        const int base = t * 16;
#pragma unroll
        for (int i = 0; i < 16; ++i) {
            run += a[PAD(base + i)];
            vals[i] = run;
        }
        float v = run;
#pragma unroll
        for (int off = 1; off < 64; off <<= 1) {
            float u = __shfl_up(v, off, 64);
            if (lane >= off) v += u;
        }
        if (lane == 63) wred1[w] = v;
        __syncthreads();
        float woff = 0.f;
        for (int i = 0; i < w; ++i) woff += wred1[i];
        const float excl = woff + v - run;
        __syncthreads();
#pragma unroll
        for (int i = 0; i < 16; ++i) a[PAD(base + i + 1)] = excl + vals[i];
        if (t == 0) a[PAD(0)] = 0.f;
        __syncthreads();
    }

    // ---- sp ListMLE ---------------------------------------------------------
    if (t == 0) { fsb[0] = a[PAD(1)]; flb[0] = 0.5f; }     // p2[0] (thres)
    if (t < NSEG) {
        int st = sent_starts[b * (NSEG + 1) + t];
        int en = sent_starts[b * (NSEG + 1) + t + 1];
        int stc = min(max(st, 0), S);
        int enc = max(min(max(en, 0), S), stc + 1);
        float score;
        if (en != -1) {
            int encc = min(enc, S);
            score = (a[PAD(encc)] - a[PAD(stc)]) / (float)(enc - stc);
        } else {
            score = a[PAD(S)] - a[PAD(S - 1)];             // p2[S-1]
        }
        fsb[1 + t] = score;
        flb[1 + t] = sp_labels[b * NSEG + t];
    }
    __syncthreads();
    float sp_loss_b = listmle_block(fsb, flb, seb, 1 + NSEG, wred1, t);

    // ---- rank ListMLE -------------------------------------------------------
    if (t == 0) { fsb[0] = p3[0]; flb[0] = 0.5f; }
    if (t < NPARA) {
        int ps = para_starts[b * NPARA + t];
        fsb[1 + t] = p3[ps];
        flb[1 + t] = para_labels[b * NPARA + t];
    }
    __syncthreads();
    float rank_loss_b = listmle_block(fsb, flb, seb, 1 + NPARA, wred1, t);

    // ---- span loss (parallel over answers) ----------------------------------
    float e_a = 0.f;
    if (t < NA) {
        const float lse0 = lse_sh[0], lse1 = lse_sh[1];
        int tsv = starts[b * NA + t];
        int tev = ends[b * NA + t];
        float lt = 0.f;
        if (tsv != -1) {
            int sf = min(max(tsv, 0), S - 1);
            float sl = (ttb[sf] == 1) ? p0[sf] : -INFINITY;
            lt += -(sl - lse0);
        }
        if (tev != -1) {
            int sf = min(max(tev, 0), S - 1);
            float el = (ttb[sf] == 1) ? p1[sf] : -INFINITY;
            lt += -(el - lse1);
        }
        float lp = -lt;
        e_a = (lp == 0.0f) ? 0.f : expf(lp);
    }
#pragma unroll
    for (int off = 4; off > 0; off >>= 1) e_a += __shfl_xor(e_a, off, 8);
    if (t == 0) {
        float logm = (e_a > 0.f) ? logf(e_a) : 0.f;
        atomicAdd(out + 0, rank_loss_b + sp_loss_b - logm);
        atomicAdd(out + 1, rank_loss_b);
        atomicAdd(out + 2, sp_loss_b);
    }
}

extern "C" void kernel_launch(void* const* d_in, const int* in_sizes, int n_in,
                              void* d_out, int out_size, void* d_ws, size_t ws_size,
                              hipStream_t stream)
{
    const float* seq         = (const float*)d_in[0];
    const int*   tt          = (const int*)  d_in[1];
    const int*   sent_starts = (const int*)  d_in[2];
    const int*   para_starts = (const int*)  d_in[3];
    const float* para_labels = (const float*)d_in[4];
    const float* sp_labels   = (const float*)d_in[5];
    const int*   starts      = (const int*)  d_in[6];
    const int*   ends        = (const int*)  d_in[7];
    const float* Wqa         = (const float*)d_in[8];
    const float* Wrank       = (const float*)d_in[10];
    const float* Wsp         = (const float*)d_in[12];

    float*  out      = (float*)d_out;
    float*  scores   = (float*)d_ws;                      // 4*B*S floats
    float4* lse_part = (float4*)(scores + 4 * (size_t)BS); // NBLK float4

    dots_kernel<<<NBLK, 256, 0, stream>>>(seq, Wqa, Wsp, Wrank, tt,
                                          scores, lse_part, out);
    batch_kernel<<<B, 256, 0, stream>>>(scores, lse_part, tt, sent_starts,
                                        para_starts, para_labels, sp_labels,
                                        starts, ends, out);
}